// Round 6
// baseline (307.269 us; speedup 1.0000x reference)
//
#include <hip/hip_runtime.h>

#define BB 32
#define CC 64
#define NN 1024

typedef __attribute__((ext_vector_type(8))) short bf8;            // 8 bf16 = 4 VGPR (MFMA A/B frag)
typedef __attribute__((ext_vector_type(4))) float f4;             // MFMA C/D frag
typedef __attribute__((ext_vector_type(4))) unsigned short us4;   // 8B packed bf16 store

__device__ __forceinline__ unsigned short f2bf(float f) {
    unsigned u = __float_as_uint(f);
    return (unsigned short)((u + 0x7fffu + ((u >> 16) & 1u)) >> 16);
}
__device__ __forceinline__ float bf2f(unsigned short u) {
    return __uint_as_float(((unsigned)u) << 16);
}

#define MFMA(a, b, c) __builtin_amdgcn_mfma_f32_16x16x32_bf16(a, b, c, 0, 0, 0)

// Async global->LDS DMA, 16 B per lane: LDS dst = wave-uniform base + lane*16.
#define GLDS(g, l)                                                              \
    __builtin_amdgcn_global_load_lds(                                           \
        (const __attribute__((address_space(1))) void*)(g),                     \
        (__attribute__((address_space(3))) void*)(l), 16, 0, 0)

// XCD-aware swizzle for 512-block grids (8 XCDs, round-robin dispatch):
// each XCD owns 4 contiguous batches (64 blocks). 512 % 8 == 0 -> bijective.
// Same mapping in every phase -> all cross-phase traffic is same-XCD L2-local.
__device__ __forceinline__ void swz512(int i, int& b, int& t0) {
    int gid = (i & 7) * 64 + (i >> 3);
    b = gid >> 4;
    t0 = (gid & 15) * 64;
}

// ---------------------------------------------------------------------------
// Manual grid barrier (graph-capture-safe; replaces grid.sync whose runtime
// barrier state breaks under hipGraph capture). Monotonic ticket: epoch e
// completes when counter reaches (e+1)*NB — no reset race. Release/acquire
// via __threadfence (agent scope: wbL2/invL2 -> cross-XCD visible). Spin is
// device-scope atomic read + s_sleep, BOUNDED so failure = wrong answer in
// finite time, never a hang. Co-residency: launch_bounds(512,4) -> VGPR<=128
// -> >=2 blocks/CU; LDS 46KB -> 3/CU; capacity >= 512 = grid.
// ---------------------------------------------------------------------------
__device__ __forceinline__ void gbar(unsigned* bar, int nb) {
    __syncthreads();  // all block stores issued & vmcnt drained
    if (threadIdx.x == 0) {
        __threadfence();  // release: write back my XCD's L2
        unsigned ticket = atomicAdd(bar, 1u);
        unsigned target = (ticket / (unsigned)nb + 1u) * (unsigned)nb;
        for (int i = 0; i < (1 << 20); ++i) {  // bounded spin (~0.2 s max)
            if (atomicAdd(bar, 0u) >= target) break;
            __builtin_amdgcn_s_sleep(2);
        }
        __threadfence();  // acquire: invalidate stale L2 lines
    }
    __syncthreads();
}

// ---------------------------------------------------------------------------
// k_all: whole pipeline in one kernel, 512 blocks x 512 threads
// (2-3 blocks/CU; LDS 46080 B). 4 phases, 3 manual grid barriers:
//  P0 prep: wmk fp32->bf16 (all blocks); wcat (w_theta|w_phi|w_mv@w_g) +
//           wmask -> bf16 (blocks 0-31).
//  P1 k1:   channel GEMMs out[192][64n] = wcat @ x-tile; 48 MFMA-tiles
//           split 6 per wave. theta->[n][c], phi/g2->[c][n].
//  P2 k23:  phase A: phi2t[k][c] = wmk @ phi^T (double-buffered GLDS pipeline,
//           counted vmcnt(3), XOR-swizzled tiles); tile kept in pT (LDS).
//           phase B: S[k] = sum_n exp(theta.phi2t) (theta chunks via GLDS,
//           vmcnt(1)); sinv = 1/S.
//  P3 k4:   attT = phi2t @ theta^T, P' = exp*Sinv, outT += g2 @ P'^T
//           (double-buffered GLDS, vmcnt(2)); epilogue wmask @ outT + x.
// LDS overlaid per phase in one 46080 B arena.
// ---------------------------------------------------------------------------
__global__ __launch_bounds__(512, 4) void k_all(
    const float* __restrict__ x, const float* __restrict__ w_phi,
    const float* __restrict__ w_theta, const float* __restrict__ w_g,
    const float* __restrict__ w_mask, const float* __restrict__ w_mv,
    const float* __restrict__ w_mk,
    unsigned short* __restrict__ theta_nc, unsigned short* __restrict__ phi_cm,
    unsigned short* __restrict__ g2_cm, float* __restrict__ sinv,
    unsigned short* __restrict__ phi2t, unsigned short* __restrict__ wmk_bf,
    unsigned short* __restrict__ wcat_bf, unsigned short* __restrict__ wmask_bf,
    unsigned* bar, float* __restrict__ out) {
    __shared__ __align__(16) unsigned short smem[23040];  // 46080 B arena
    const int tid = threadIdx.x;
    const int bid = blockIdx.x;
    const int w = tid >> 6, lane = tid & 63, l16 = lane & 15, q = lane >> 4;
    int b, t0;
    swz512(bid, b, t0);
    const size_t bo = (size_t)b * CC * NN;
    const int srow = w * 8 + (lane >> 3);             // staged row (linear LDS dst)
    const int scol = ((lane & 7) ^ (lane >> 3)) * 8;  // pre-swizzled src col (shorts)

    // ================= P0: prep =================
    {
        int i4 = (bid * 512 + tid) * 4;  // 512*512*4 = 1,048,576 = NN*NN
        float4 v = *(const float4*)(w_mk + i4);
        us4 r;
        r.x = f2bf(v.x); r.y = f2bf(v.y); r.z = f2bf(v.z); r.w = f2bf(v.w);
        *(us4*)(wmk_bf + i4) = r;
        if (bid < 32) {
            int idx = bid * 512 + tid;  // 0..16383
            if (idx < 4096) {
                wcat_bf[idx] = f2bf(w_theta[idx]);
            } else if (idx < 8192) {
                wcat_bf[idx] = f2bf(w_phi[idx - 4096]);
            } else if (idx < 12288) {
                int s = idx - 8192, d = s >> 6, e = s & 63;
                float acc = 0.f;
                for (int c = 0; c < 64; ++c) acc += w_mv[d * 64 + c] * w_g[c * 64 + e];
                wcat_bf[idx] = f2bf(acc);
            } else {
                wmask_bf[idx - 12288] = f2bf(w_mask[idx - 12288]);
            }
        }
    }
    gbar(bar, 512);

    // ================= P1: channel GEMMs (k1) =================
    {
        unsigned short* xT = smem;  // [64][72] bf16 = 9216 B
        int n0 = t0;
#pragma unroll
        for (int i = 0; i < 2; ++i) {
            int idx = i * 512 + tid;  // 1024 float4 = 64c x 16
            int c = idx >> 4, n4 = (idx & 15) * 4;
            float4 v = *(const float4*)(x + bo + (size_t)c * NN + n0 + n4);
            xT[(n4 + 0) * 72 + c] = f2bf(v.x);
            xT[(n4 + 1) * 72 + c] = f2bf(v.y);
            xT[(n4 + 2) * 72 + c] = f2bf(v.z);
            xT[(n4 + 3) * 72 + c] = f2bf(v.w);
        }
        __syncthreads();
        bf8 bF[4][2];
#pragma unroll
        for (int ct = 0; ct < 4; ++ct) {
            bF[ct][0] = *(const bf8*)&xT[(ct * 16 + l16) * 72 + q * 8];
            bF[ct][1] = *(const bf8*)&xT[(ct * 16 + l16) * 72 + 32 + q * 8];
        }
        // 48 (rowTile, colTile) MFMA tiles; 8 waves x 6 each (wave-uniform split)
#pragma unroll
        for (int i = 0; i < 6; ++i) {
            int t = w * 6 + i;
            int R = (t >> 2) * 16, ct = t & 3;
            const unsigned short* wa = wcat_bf + (R + l16) * 64 + q * 8;
            bf8 a0 = *(const bf8*)wa;
            bf8 a1 = *(const bf8*)(wa + 32);
            int which = R >> 6, rb = R & 63;  // wave-uniform
            f4 acc = {0.f, 0.f, 0.f, 0.f};
            acc = MFMA(a0, bF[ct][0], acc);
            acc = MFMA(a1, bF[ct][1], acc);
            int n = n0 + ct * 16 + l16;
            if (which == 0) {  // theta: [n][c] layout, rows o contiguous per lane
                us4 tt;
                tt.x = f2bf(acc[0]); tt.y = f2bf(acc[1]);
                tt.z = f2bf(acc[2]); tt.w = f2bf(acc[3]);
                *(us4*)&theta_nc[bo + (size_t)n * 64 + rb + q * 4] = tt;
            } else {
                unsigned short* dst = (which == 1 ? phi_cm : g2_cm) + bo;
#pragma unroll
                for (int r = 0; r < 4; ++r)
                    dst[(size_t)(rb + q * 4 + r) * NN + n] = f2bf(acc[r]);
            }
        }
    }
    gbar(bar, 512);

    // ================= P2: phi2t + stats (k23) =================
    {
        int k0 = t0;
        unsigned short* bT0 = smem;  // [2][4096] tiles/chunks
        unsigned short(*pT)[72] = (unsigned short(*)[72])(smem + 8192);  // [64][72]
        float(*sred)[32] = (float(*)[32])(void*)(smem + 12800);          // [8][32]
        // ---- phase A: phi2t tile [64k][64c] = wmk @ phi^T ----
        int ks = w & 3, ch = w >> 2;
        const unsigned short* gsrc = phi_cm + bo + (size_t)srow * NN + scol;
        const unsigned short* arow = wmk_bf + (size_t)(k0 + ks * 16 + l16) * NN + q * 8;
        f4 acc[2];
        acc[0] = (f4){0.f, 0.f, 0.f, 0.f};
        acc[1] = (f4){0.f, 0.f, 0.f, 0.f};
        bf8 aC0 = *(const bf8*)(arow);
        bf8 aC1 = *(const bf8*)(arow + 32);
        GLDS(gsrc, bT0 + w * 512);
        __syncthreads();  // prologue: tile 0 + A rows 0 ready (drains vmcnt)
#pragma unroll 2
        for (int mc = 0; mc < 16; ++mc) {
            const unsigned short* bTc = bT0 + (mc & 1) * 4096;
            bf8 aN0 = aC0, aN1 = aC1;
            if (mc < 15) {
                int mn = (mc + 1) * 64;
                aN0 = *(const bf8*)(arow + mn);
                aN1 = *(const bf8*)(arow + mn + 32);
                GLDS(gsrc + mn, bT0 + ((mc + 1) & 1) * 4096 + w * 512);
                asm volatile("s_waitcnt vmcnt(3)" ::: "memory");  // cur tile + cur A done
            } else {
                asm volatile("s_waitcnt vmcnt(0)" ::: "memory");
            }
            __builtin_amdgcn_s_barrier();
            __builtin_amdgcn_sched_barrier(0);
#pragma unroll
            for (int t = 0; t < 2; ++t) {
                int row = (ch * 2 + t) * 16 + l16;
                int sw = (row & 7) * 8;
                bf8 b0 = *(const bf8*)&bTc[row * 64 + ((q * 8) ^ sw)];
                bf8 b1 = *(const bf8*)&bTc[row * 64 + ((32 + q * 8) ^ sw)];
                acc[t] = MFMA(aC0, b0, acc[t]);
                acc[t] = MFMA(aC1, b1, acc[t]);
            }
            __builtin_amdgcn_s_barrier();  // all readers done -> next overwrite safe
            __builtin_amdgcn_sched_barrier(0);
            aC0 = aN0;
            aC1 = aN1;
        }
        // epilogue A: tile -> pT (LDS) + phi2t (global, needed by P3)
        unsigned short* prow = phi2t + bo;
#pragma unroll
        for (int t = 0; t < 2; ++t) {
            int ccol = (ch * 2 + t) * 16 + l16;
#pragma unroll
            for (int r = 0; r < 4; ++r) {
                int krow = ks * 16 + q * 4 + r;
                unsigned short v = f2bf(acc[t][r]);
                pT[krow][ccol] = v;
                prow[(size_t)(k0 + krow) * 64 + ccol] = v;
            }
        }
        // ---- phase B: S[k] over all n ----
        int rg = w & 3, th = w >> 2;
        const unsigned short* thsrc = theta_nc + bo + (size_t)srow * 64 + scol;
        GLDS(thsrc, bT0 + w * 512);  // theta chunk 0 (overlaps pT write drain)
        __syncthreads();             // drains pT ds_writes + chunk-0 DMA
        bf8 pF[2][2];
#pragma unroll
        for (int t = 0; t < 2; ++t)
#pragma unroll
            for (int kc = 0; kc < 2; ++kc)
                pF[t][kc] = *(const bf8*)&pT[(th * 2 + t) * 16 + l16][kc * 32 + q * 8];
        float s[2] = {0.f, 0.f};
#pragma unroll 2
        for (int nc = 0; nc < 16; ++nc) {
            const unsigned short* tTc = bT0 + (nc & 1) * 4096;
            if (nc < 15) {
                GLDS(thsrc + (nc + 1) * 4096, bT0 + ((nc + 1) & 1) * 4096 + w * 512);
                asm volatile("s_waitcnt vmcnt(1)" ::: "memory");  // cur chunk staged
            } else {
                asm volatile("s_waitcnt vmcnt(0)" ::: "memory");
            }
            __builtin_amdgcn_s_barrier();
            __builtin_amdgcn_sched_barrier(0);
            int r = rg * 16 + l16;
            int sw = (r & 7);
            bf8 a0 = *(const bf8*)&tTc[r * 64 + ((q ^ sw) * 8)];
            bf8 a1 = *(const bf8*)&tTc[r * 64 + (((4 + q) ^ sw) * 8)];
#pragma unroll
            for (int t = 0; t < 2; ++t) {
                f4 at = {0.f, 0.f, 0.f, 0.f};
                at = MFMA(a0, pF[t][0], at);
                at = MFMA(a1, pF[t][1], at);
                s[t] += __expf(at[0]) + __expf(at[1]) + __expf(at[2]) + __expf(at[3]);
            }
            __builtin_amdgcn_s_barrier();  // readers done -> next overwrite safe
            __builtin_amdgcn_sched_barrier(0);
        }
#pragma unroll
        for (int t = 0; t < 2; ++t) {
            s[t] += __shfl_xor(s[t], 16, 64);
            s[t] += __shfl_xor(s[t], 32, 64);
        }
        if (q == 0) {
            sred[w][l16] = s[0];
            sred[w][16 + l16] = s[1];
        }
        __syncthreads();
        if (tid < 64) {
            int th2 = tid >> 5, rem = tid & 31;
            float S = sred[th2 * 4 + 0][rem] + sred[th2 * 4 + 1][rem] +
                      sred[th2 * 4 + 2][rem] + sred[th2 * 4 + 3][rem];
            sinv[(size_t)b * NN + k0 + tid] = 1.f / S;
        }
    }
    gbar(bar, 512);

    // ================= P3: attention output (k4) =================
    {
        int n0 = t0;
        float* svs_l = (float*)(smem + 20992);  // 1024 f32
        int ws = w & 3, ph = w >> 2;
        int nl = ws * 16 + l16;  // lane's n (frag col); P rows wave-private
        const unsigned short* p2b = phi2t + bo;
        const unsigned short* g2b = g2_cm + bo;
        if (tid < 256) *(f4*)&svs_l[tid * 4] = *(const f4*)(sinv + (size_t)b * NN + tid * 4);
        bf8 thB[2];
#pragma unroll
        for (int kc = 0; kc < 2; ++kc)
            thB[kc] = *(const bf8*)(theta_nc + bo + (size_t)(n0 + nl) * 64 + kc * 32 + q * 8);
        f4 accO[4];
#pragma unroll
        for (int ct = 0; ct < 4; ++ct) accO[ct] = (f4){0.f, 0.f, 0.f, 0.f};
        // prologue: stage chunk 0 into buf 0
        GLDS(p2b + (size_t)srow * 64 + scol, smem + w * 512);
        GLDS(g2b + (size_t)srow * NN + scol, smem + 4096 + w * 512);
        __syncthreads();  // drains prologue DMA + svs/thB loads
#pragma unroll 2
        for (int mc = 0; mc < 16; ++mc) {
            unsigned short* aT = smem + (mc & 1) * 8192;  // phi2t chunk [m64][c64]
            unsigned short* gT = aT + 4096;               // g2 chunk [c64][m64]
            if (mc < 15) {
                int mn = (mc + 1) * 64;
                unsigned short* aN = smem + ((mc + 1) & 1) * 8192;
                GLDS(p2b + (size_t)(mn + srow) * 64 + scol, aN + w * 512);
                GLDS(g2b + (size_t)srow * NN + mn + scol, aN + 4096 + w * 512);
                asm volatile("s_waitcnt vmcnt(2)" ::: "memory");  // cur chunk staged
            } else {
                asm volatile("s_waitcnt vmcnt(0)" ::: "memory");
            }
            __builtin_amdgcn_s_barrier();
            __builtin_amdgcn_sched_barrier(0);
            int m0 = mc * 64;
            unsigned short* Pr = smem + 16384 + nl * 72 + ph * 32;
            int swz = (l16 & 7) * 8;
            // GEMM1: att rows (ph-half of chunk) x 16 n-cols; P' = exp * Sinv
#pragma unroll
            for (int mrr = 0; mrr < 2; ++mrr) {
                int rowA = ph * 32 + mrr * 16 + l16;
                bf8 a0 = *(const bf8*)&aT[rowA * 64 + ((q * 8) ^ swz)];
                bf8 a1 = *(const bf8*)&aT[rowA * 64 + ((32 + q * 8) ^ swz)];
                f4 at = {0.f, 0.f, 0.f, 0.f};
                at = MFMA(a0, thB[0], at);
                at = MFMA(a1, thB[1], at);
                f4 sv = *(const f4*)&svs_l[m0 + ph * 32 + mrr * 16 + q * 4];
                us4 pk;
                pk.x = f2bf(__expf(at[0]) * sv[0]);
                pk.y = f2bf(__expf(at[1]) * sv[1]);
                pk.z = f2bf(__expf(at[2]) * sv[2]);
                pk.w = f2bf(__expf(at[3]) * sv[3]);
                *(us4*)&Pr[mrr * 16 + q * 4] = pk;
            }
            // GEMM2: outT[c][n] += g2[c][k in ph-half] * P'[n][k]
            bf8 pF = *(const bf8*)&Pr[q * 8];
#pragma unroll
            for (int ct = 0; ct < 4; ++ct) {
                int rowG = ct * 16 + l16;
                bf8 g0 = *(const bf8*)&gT[rowG * 64 + (((ph * 32) + q * 8) ^ swz)];
                accO[ct] = MFMA(g0, pF, accO[ct]);
            }
            __builtin_amdgcn_s_barrier();  // readers done -> next overwrite safe
            __builtin_amdgcn_sched_barrier(0);
        }
        // ph-pair reduction (o_red aliases buf region; o_lds after it)
        float* o_red = (float*)smem;          // [64][68] f32 = 17408 B
        unsigned short* o_lds = smem + 8704;  // [64][72] bf16
        if (ph == 1) {
#pragma unroll
            for (int ct = 0; ct < 4; ++ct)
#pragma unroll
                for (int r = 0; r < 4; ++r) o_red[(ct * 16 + q * 4 + r) * 68 + nl] = accO[ct][r];
        }
        __syncthreads();
        if (ph == 0) {
#pragma unroll
            for (int ct = 0; ct < 4; ++ct) {
                us4 ov;
                ov.x = f2bf(accO[ct][0] + o_red[(ct * 16 + q * 4 + 0) * 68 + nl]);
                ov.y = f2bf(accO[ct][1] + o_red[(ct * 16 + q * 4 + 1) * 68 + nl]);
                ov.z = f2bf(accO[ct][2] + o_red[(ct * 16 + q * 4 + 2) * 68 + nl]);
                ov.w = f2bf(accO[ct][3] + o_red[(ct * 16 + q * 4 + 3) * 68 + nl]);
                *(us4*)&o_lds[nl * 72 + ct * 16 + q * 4] = ov;
            }
        }
        __syncthreads();
        // epilogue: finalT[o][n] = wmask @ outT + x ; o-rows split across ph
        bf8 oB0 = *(const bf8*)&o_lds[nl * 72 + q * 8];
        bf8 oB1 = *(const bf8*)&o_lds[nl * 72 + 32 + q * 8];
#pragma unroll
        for (int t2 = 0; t2 < 2; ++t2) {
            int tr = ph * 2 + t2;
            const unsigned short* wa = wmask_bf + (tr * 16 + l16) * 64 + q * 8;
            bf8 w0 = *(const bf8*)wa;
            bf8 w1 = *(const bf8*)(wa + 32);
            f4 accF = {0.f, 0.f, 0.f, 0.f};
            accF = MFMA(w0, oB0, accF);
            accF = MFMA(w1, oB1, accF);
#pragma unroll
            for (int r = 0; r < 4; ++r) {
                size_t ix = bo + (size_t)(tr * 16 + q * 4 + r) * NN + n0 + nl;
                out[ix] = accF[r] + x[ix];
            }
        }
    }
}

// ---------------------------------------------------------------------------
extern "C" void kernel_launch(void* const* d_in, const int* in_sizes, int n_in,
                              void* d_out, int out_size, void* d_ws, size_t ws_size,
                              hipStream_t stream) {
    const float* x       = (const float*)d_in[0];
    const float* w_phi   = (const float*)d_in[1];
    const float* w_theta = (const float*)d_in[2];
    const float* w_g     = (const float*)d_in[3];
    const float* w_mask  = (const float*)d_in[4];
    const float* w_mv    = (const float*)d_in[5];
    const float* w_mk    = (const float*)d_in[6];
    float* out = (float*)d_out;

    const size_t CN = (size_t)BB * CC * NN;  // 2,097,152 elements
    char* p = (char*)d_ws;
    unsigned short* theta_nc = (unsigned short*)p; p += CN * 2;
    unsigned short* phi_cm = (unsigned short*)p;   p += CN * 2;
    unsigned short* g2_cm = (unsigned short*)p;    p += CN * 2;
    float* sinv = (float*)p;                       p += CN * 2;  // uses 128 KB of slot
    unsigned short* phi2t = (unsigned short*)p;    p += CN * 2;
    unsigned short* wmk_bf = (unsigned short*)p;   p += (size_t)NN * NN * 2;
    unsigned short* wcat_bf = (unsigned short*)p;  p += 192 * 64 * 2;
    unsigned short* wmask_bf = (unsigned short*)p; p += 4096 * 2;
    unsigned* bar = (unsigned*)p;                  p += 256;  // grid-barrier ticket

    hipMemsetAsync((void*)bar, 0, 256, stream);  // captured into graph, runs per-iter
    k_all<<<512, 512, 0, stream>>>(x, w_phi, w_theta, w_g, w_mask, w_mv, w_mk,
                                   theta_nc, phi_cm, g2_cm, sinv, phi2t,
                                   wmk_bf, wcat_bf, wmask_bf, bar, out);
}

// Round 7
// 287.469 us; speedup vs baseline: 1.0689x; 1.0689x over previous
//
#include <hip/hip_runtime.h>

#define BB 32
#define CC 64
#define NN 1024

typedef __attribute__((ext_vector_type(8))) short bf8;            // 8 bf16 = 4 VGPR (MFMA A/B frag)
typedef __attribute__((ext_vector_type(4))) float f4;             // MFMA C/D frag
typedef __attribute__((ext_vector_type(4))) unsigned short us4;   // 8B packed bf16 store

__device__ __forceinline__ unsigned short f2bf(float f) {
    unsigned u = __float_as_uint(f);
    return (unsigned short)((u + 0x7fffu + ((u >> 16) & 1u)) >> 16);
}
__device__ __forceinline__ float bf2f(unsigned short u) {
    return __uint_as_float(((unsigned)u) << 16);
}

#define MFMA(a, b, c) __builtin_amdgcn_mfma_f32_16x16x32_bf16(a, b, c, 0, 0, 0)

// Async global->LDS DMA, 16 B per lane: LDS dst = wave-uniform base + lane*16.
#define GLDS(g, l)                                                              \
    __builtin_amdgcn_global_load_lds(                                           \
        (const __attribute__((address_space(1))) void*)(g),                     \
        (__attribute__((address_space(3))) void*)(l), 16, 0, 0)

// XCD-aware swizzle for 512-block grids (8 XCDs, round-robin dispatch):
// each XCD owns 4 contiguous batches (64 blocks). 512 % 8 == 0 -> bijective.
__device__ __forceinline__ void swz512(int i, int& b, int& t0) {
    int gid = (i & 7) * 64 + (i >> 3);
    b = gid >> 4;
    t0 = (gid & 15) * 64;
}

// ---------------------------------------------------------------------------
// Manual grid barrier, graph-capture-safe. Round-6 lesson: polling with
// atomicAdd(bar,0) is an RMW -> 512 spinners create a serialized RMW storm
// (~60 us/barrier). Fix: arrival = ONE fetch_add per block; spin = relaxed
// agent-scope atomic LOAD (concurrent, no line bouncing) + s_sleep backoff.
// Monotonic ticket (no reset race); bounded spin -> no hang. Release/acquire
// via __threadfence (L2 wb/inv, cross-XCD). Co-residency: 512 blocks, 46KB
// LDS + VGPR<=128 -> >=2 blocks/CU on 256 CUs.
// ---------------------------------------------------------------------------
__device__ __forceinline__ void gbar(unsigned* bar, unsigned nb) {
    __syncthreads();  // all waves' stores issued & drained
    if (threadIdx.x == 0) {
        __threadfence();  // release: write back my XCD's L2
        unsigned ticket = __hip_atomic_fetch_add(bar, 1u, __ATOMIC_RELAXED,
                                                 __HIP_MEMORY_SCOPE_AGENT);
        unsigned target = (ticket / nb + 1u) * nb;
        for (int i = 0; i < (1 << 18); ++i) {  // bounded (~100 ms max)
            if (__hip_atomic_load(bar, __ATOMIC_RELAXED,
                                  __HIP_MEMORY_SCOPE_AGENT) >= target)
                break;
            __builtin_amdgcn_s_sleep(16);  // ~1024 cy between polls
        }
        __threadfence();  // acquire: invalidate stale lines
    }
    __syncthreads();
}

// ---------------------------------------------------------------------------
// k_all: whole pipeline, 512 blocks x 512 threads, TWO grid barriers.
//  P01: wmk fp32->bf16 (distributed); wmask->bf16 (blocks 0-7); wcat
//       (w_theta|w_phi|w_mv@w_g) computed REDUNDANTLY per block into LDS
//       (removes the P0->P1 rendezvous); then channel GEMMs
//       out[192][64n] = wcat @ x-tile; theta->[n][c], phi/g2->[c][n].
//  P2:  phase A: phi2t[k][c] = wmk @ phi^T (double-buffered GLDS, counted
//       vmcnt(3), XOR-swizzle); tile kept in pT. phase B: S[k] =
//       sum_n exp(theta.phi2t) (theta chunks via GLDS, vmcnt(1)); sinv=1/S.
//  P3:  attT = phi2t @ theta^T, P' = exp*Sinv, outT += g2 @ P'^T
//       (double-buffered GLDS, vmcnt(2)); epilogue wmask @ outT + x.
// LDS overlaid per phase in one 46080 B arena.
// ---------------------------------------------------------------------------
__global__ __launch_bounds__(512, 4) void k_all(
    const float* __restrict__ x, const float* __restrict__ w_phi,
    const float* __restrict__ w_theta, const float* __restrict__ w_g,
    const float* __restrict__ w_mask, const float* __restrict__ w_mv,
    const float* __restrict__ w_mk,
    unsigned short* __restrict__ theta_nc, unsigned short* __restrict__ phi_cm,
    unsigned short* __restrict__ g2_cm, float* __restrict__ sinv,
    unsigned short* __restrict__ phi2t, unsigned short* __restrict__ wmk_bf,
    unsigned short* __restrict__ wmask_bf, unsigned* bar,
    float* __restrict__ out) {
    __shared__ __align__(16) unsigned short smem[23040];  // 46080 B arena
    const int tid = threadIdx.x;
    const int bid = blockIdx.x;
    const int w = tid >> 6, lane = tid & 63, l16 = lane & 15, q = lane >> 4;
    int b, t0;
    swz512(bid, b, t0);
    const size_t bo = (size_t)b * CC * NN;
    const int srow = w * 8 + (lane >> 3);             // staged row (linear LDS dst)
    const int scol = ((lane & 7) ^ (lane >> 3)) * 8;  // pre-swizzled src col (shorts)

    // ================= P01: prep + channel GEMMs =================
    {
        unsigned short* wcatL = smem;       // [192][64] swizzled = 24576 B
        unsigned short* xT = smem + 12288;  // [64][72] = 9216 B
        // wmk fp32->bf16, distributed across all 512 blocks
        int i4 = (bid * 512 + tid) * 4;  // 512*512*4 = NN*NN
        float4 v = *(const float4*)(w_mk + i4);
        us4 r;
        r.x = f2bf(v.x); r.y = f2bf(v.y); r.z = f2bf(v.z); r.w = f2bf(v.w);
        *(us4*)(wmk_bf + i4) = r;
        if (bid < 8) {  // wmask (4096) -> global; consumed only in P3
            int idx = bid * 512 + tid;
            wmask_bf[idx] = f2bf(w_mask[idx]);
        }
        // wcat -> LDS, swizzled (col8 ^= row&7), redundant per block
#pragma unroll
        for (int i = 0; i < 8; ++i) {
            int idx = i * 512 + tid;  // 0..4095
            int row = idx >> 6, e = idx & 63;
            int sw = (((e >> 3) ^ (row & 7)) << 3) | (e & 7);
            wcatL[row * 64 + sw] = f2bf(w_theta[idx]);
            int row2 = row + 64;
            int sw2 = (((e >> 3) ^ (row2 & 7)) << 3) | (e & 7);
            wcatL[row2 * 64 + sw2] = f2bf(w_phi[idx]);
        }
#pragma unroll 2
        for (int i = 0; i < 8; ++i) {
            int idx = i * 512 + tid;
            int d = idx >> 6, e = idx & 63;
            float a = 0.f;
            for (int c = 0; c < 64; ++c) a += w_mv[d * 64 + c] * w_g[c * 64 + e];
            int row = 128 + d;
            int sw = (((e >> 3) ^ (row & 7)) << 3) | (e & 7);
            wcatL[row * 64 + sw] = f2bf(a);
        }
        // x tile -> xT[64n][72c]
        int n0 = t0;
#pragma unroll
        for (int i = 0; i < 2; ++i) {
            int idx = i * 512 + tid;  // 1024 float4 = 64c x 16
            int c = idx >> 4, n4 = (idx & 15) * 4;
            float4 xv = *(const float4*)(x + bo + (size_t)c * NN + n0 + n4);
            xT[(n4 + 0) * 72 + c] = f2bf(xv.x);
            xT[(n4 + 1) * 72 + c] = f2bf(xv.y);
            xT[(n4 + 2) * 72 + c] = f2bf(xv.z);
            xT[(n4 + 3) * 72 + c] = f2bf(xv.w);
        }
        __syncthreads();
        bf8 bF[4][2];
#pragma unroll
        for (int ct = 0; ct < 4; ++ct) {
            bF[ct][0] = *(const bf8*)&xT[(ct * 16 + l16) * 72 + q * 8];
            bF[ct][1] = *(const bf8*)&xT[(ct * 16 + l16) * 72 + 32 + q * 8];
        }
        // 48 (rowTile, colTile) MFMA tiles; 8 waves x 6 each
#pragma unroll
        for (int i = 0; i < 6; ++i) {
            int t = w * 6 + i;
            int R = (t >> 2) * 16, ct = t & 3;
            int rowA = R + l16, s8 = rowA & 7;
            bf8 a0 = *(const bf8*)&wcatL[rowA * 64 + ((q ^ s8) << 3)];
            bf8 a1 = *(const bf8*)&wcatL[rowA * 64 + (((4 + q) ^ s8) << 3)];
            int which = R >> 6, rb = R & 63;  // wave-uniform
            f4 acc = {0.f, 0.f, 0.f, 0.f};
            acc = MFMA(a0, bF[ct][0], acc);
            acc = MFMA(a1, bF[ct][1], acc);
            int n = n0 + ct * 16 + l16;
            if (which == 0) {  // theta: [n][c] layout
                us4 tt;
                tt.x = f2bf(acc[0]); tt.y = f2bf(acc[1]);
                tt.z = f2bf(acc[2]); tt.w = f2bf(acc[3]);
                *(us4*)&theta_nc[bo + (size_t)n * 64 + rb + q * 4] = tt;
            } else {
                unsigned short* dst = (which == 1 ? phi_cm : g2_cm) + bo;
#pragma unroll
                for (int rr = 0; rr < 4; ++rr)
                    dst[(size_t)(rb + q * 4 + rr) * NN + n] = f2bf(acc[rr]);
            }
        }
    }
    gbar(bar, 512);

    // ================= P2: phi2t + stats =================
    {
        int k0 = t0;
        unsigned short* bT0 = smem;  // [2][4096] tiles/chunks
        unsigned short(*pT)[72] = (unsigned short(*)[72])(smem + 8192);  // [64][72]
        float(*sred)[32] = (float(*)[32])(void*)(smem + 12800);          // [8][32]
        // ---- phase A: phi2t tile [64k][64c] = wmk @ phi^T ----
        int ks = w & 3, ch = w >> 2;
        const unsigned short* gsrc = phi_cm + bo + (size_t)srow * NN + scol;
        const unsigned short* arow = wmk_bf + (size_t)(k0 + ks * 16 + l16) * NN + q * 8;
        f4 acc[2];
        acc[0] = (f4){0.f, 0.f, 0.f, 0.f};
        acc[1] = (f4){0.f, 0.f, 0.f, 0.f};
        bf8 aC0 = *(const bf8*)(arow);
        bf8 aC1 = *(const bf8*)(arow + 32);
        GLDS(gsrc, bT0 + w * 512);
        __syncthreads();  // prologue: tile 0 + A rows 0 ready
#pragma unroll 2
        for (int mc = 0; mc < 16; ++mc) {
            const unsigned short* bTc = bT0 + (mc & 1) * 4096;
            bf8 aN0 = aC0, aN1 = aC1;
            if (mc < 15) {
                int mn = (mc + 1) * 64;
                aN0 = *(const bf8*)(arow + mn);
                aN1 = *(const bf8*)(arow + mn + 32);
                GLDS(gsrc + mn, bT0 + ((mc + 1) & 1) * 4096 + w * 512);
                asm volatile("s_waitcnt vmcnt(3)" ::: "memory");  // cur tile + cur A done
            } else {
                asm volatile("s_waitcnt vmcnt(0)" ::: "memory");
            }
            __builtin_amdgcn_s_barrier();
            __builtin_amdgcn_sched_barrier(0);
#pragma unroll
            for (int t = 0; t < 2; ++t) {
                int row = (ch * 2 + t) * 16 + l16;
                int sw = (row & 7) * 8;
                bf8 b0 = *(const bf8*)&bTc[row * 64 + ((q * 8) ^ sw)];
                bf8 b1 = *(const bf8*)&bTc[row * 64 + ((32 + q * 8) ^ sw)];
                acc[t] = MFMA(aC0, b0, acc[t]);
                acc[t] = MFMA(aC1, b1, acc[t]);
            }
            __builtin_amdgcn_s_barrier();  // all readers done -> next overwrite safe
            __builtin_amdgcn_sched_barrier(0);
            aC0 = aN0;
            aC1 = aN1;
        }
        // epilogue A: tile -> pT (LDS) + phi2t (global, needed by P3)
        unsigned short* prow = phi2t + bo;
#pragma unroll
        for (int t = 0; t < 2; ++t) {
            int ccol = (ch * 2 + t) * 16 + l16;
#pragma unroll
            for (int rr = 0; rr < 4; ++rr) {
                int krow = ks * 16 + q * 4 + rr;
                unsigned short vv = f2bf(acc[t][rr]);
                pT[krow][ccol] = vv;
                prow[(size_t)(k0 + krow) * 64 + ccol] = vv;
            }
        }
        // ---- phase B: S[k] over all n ----
        int rg = w & 3, th = w >> 2;
        const unsigned short* thsrc = theta_nc + bo + (size_t)srow * 64 + scol;
        GLDS(thsrc, bT0 + w * 512);  // theta chunk 0 (overlaps pT write drain)
        __syncthreads();             // drains pT ds_writes + chunk-0 DMA
        bf8 pF[2][2];
#pragma unroll
        for (int t = 0; t < 2; ++t)
#pragma unroll
            for (int kc = 0; kc < 2; ++kc)
                pF[t][kc] = *(const bf8*)&pT[(th * 2 + t) * 16 + l16][kc * 32 + q * 8];
        float s[2] = {0.f, 0.f};
#pragma unroll 2
        for (int nc = 0; nc < 16; ++nc) {
            const unsigned short* tTc = bT0 + (nc & 1) * 4096;
            if (nc < 15) {
                GLDS(thsrc + (nc + 1) * 4096, bT0 + ((nc + 1) & 1) * 4096 + w * 512);
                asm volatile("s_waitcnt vmcnt(1)" ::: "memory");  // cur chunk staged
            } else {
                asm volatile("s_waitcnt vmcnt(0)" ::: "memory");
            }
            __builtin_amdgcn_s_barrier();
            __builtin_amdgcn_sched_barrier(0);
            int rr = rg * 16 + l16;
            int sw = (rr & 7);
            bf8 a0 = *(const bf8*)&tTc[rr * 64 + ((q ^ sw) * 8)];
            bf8 a1 = *(const bf8*)&tTc[rr * 64 + (((4 + q) ^ sw) * 8)];
#pragma unroll
            for (int t = 0; t < 2; ++t) {
                f4 at = {0.f, 0.f, 0.f, 0.f};
                at = MFMA(a0, pF[t][0], at);
                at = MFMA(a1, pF[t][1], at);
                s[t] += __expf(at[0]) + __expf(at[1]) + __expf(at[2]) + __expf(at[3]);
            }
            __builtin_amdgcn_s_barrier();  // readers done -> next overwrite safe
            __builtin_amdgcn_sched_barrier(0);
        }
#pragma unroll
        for (int t = 0; t < 2; ++t) {
            s[t] += __shfl_xor(s[t], 16, 64);
            s[t] += __shfl_xor(s[t], 32, 64);
        }
        if (q == 0) {
            sred[w][l16] = s[0];
            sred[w][16 + l16] = s[1];
        }
        __syncthreads();
        if (tid < 64) {
            int th2 = tid >> 5, rem = tid & 31;
            float S = sred[th2 * 4 + 0][rem] + sred[th2 * 4 + 1][rem] +
                      sred[th2 * 4 + 2][rem] + sred[th2 * 4 + 3][rem];
            sinv[(size_t)b * NN + k0 + tid] = 1.f / S;
        }
    }
    gbar(bar, 512);

    // ================= P3: attention output =================
    {
        int n0 = t0;
        float* svs_l = (float*)(smem + 20992);  // 1024 f32
        int ws = w & 3, ph = w >> 2;
        int nl = ws * 16 + l16;  // lane's n (frag col); P rows wave-private
        const unsigned short* p2b = phi2t + bo;
        const unsigned short* g2b = g2_cm + bo;
        if (tid < 256) *(f4*)&svs_l[tid * 4] = *(const f4*)(sinv + (size_t)b * NN + tid * 4);
        bf8 thB[2];
#pragma unroll
        for (int kc = 0; kc < 2; ++kc)
            thB[kc] = *(const bf8*)(theta_nc + bo + (size_t)(n0 + nl) * 64 + kc * 32 + q * 8);
        f4 accO[4];
#pragma unroll
        for (int ct = 0; ct < 4; ++ct) accO[ct] = (f4){0.f, 0.f, 0.f, 0.f};
        // prologue: stage chunk 0 into buf 0
        GLDS(p2b + (size_t)srow * 64 + scol, smem + w * 512);
        GLDS(g2b + (size_t)srow * NN + scol, smem + 4096 + w * 512);
        __syncthreads();  // drains prologue DMA + svs/thB loads
#pragma unroll 2
        for (int mc = 0; mc < 16; ++mc) {
            unsigned short* aT = smem + (mc & 1) * 8192;  // phi2t chunk [m64][c64]
            unsigned short* gT = aT + 4096;               // g2 chunk [c64][m64]
            if (mc < 15) {
                int mn = (mc + 1) * 64;
                unsigned short* aN = smem + ((mc + 1) & 1) * 8192;
                GLDS(p2b + (size_t)(mn + srow) * 64 + scol, aN + w * 512);
                GLDS(g2b + (size_t)srow * NN + mn + scol, aN + 4096 + w * 512);
                asm volatile("s_waitcnt vmcnt(2)" ::: "memory");  // cur chunk staged
            } else {
                asm volatile("s_waitcnt vmcnt(0)" ::: "memory");
            }
            __builtin_amdgcn_s_barrier();
            __builtin_amdgcn_sched_barrier(0);
            int m0 = mc * 64;
            unsigned short* Pr = smem + 16384 + nl * 72 + ph * 32;
            int swz = (l16 & 7) * 8;
            // GEMM1: att rows (ph-half of chunk) x 16 n-cols; P' = exp * Sinv
#pragma unroll
            for (int mrr = 0; mrr < 2; ++mrr) {
                int rowA = ph * 32 + mrr * 16 + l16;
                bf8 a0 = *(const bf8*)&aT[rowA * 64 + ((q * 8) ^ swz)];
                bf8 a1 = *(const bf8*)&aT[rowA * 64 + ((32 + q * 8) ^ swz)];
                f4 at = {0.f, 0.f, 0.f, 0.f};
                at = MFMA(a0, thB[0], at);
                at = MFMA(a1, thB[1], at);
                f4 sv = *(const f4*)&svs_l[m0 + ph * 32 + mrr * 16 + q * 4];
                us4 pk;
                pk.x = f2bf(__expf(at[0]) * sv[0]);
                pk.y = f2bf(__expf(at[1]) * sv[1]);
                pk.z = f2bf(__expf(at[2]) * sv[2]);
                pk.w = f2bf(__expf(at[3]) * sv[3]);
                *(us4*)&Pr[mrr * 16 + q * 4] = pk;
            }
            // GEMM2: outT[c][n] += g2[c][k in ph-half] * P'[n][k]
            bf8 pF = *(const bf8*)&Pr[q * 8];
#pragma unroll
            for (int ct = 0; ct < 4; ++ct) {
                int rowG = ct * 16 + l16;
                bf8 g0 = *(const bf8*)&gT[rowG * 64 + (((ph * 32) + q * 8) ^ swz)];
                accO[ct] = MFMA(g0, pF, accO[ct]);
            }
            __builtin_amdgcn_s_barrier();  // readers done -> next overwrite safe
            __builtin_amdgcn_sched_barrier(0);
        }
        // ph-pair reduction (o_red aliases buf region; o_lds after it)
        float* o_red = (float*)smem;          // [64][68] f32 = 17408 B
        unsigned short* o_lds = smem + 8704;  // [64][72] bf16
        if (ph == 1) {
#pragma unroll
            for (int ct = 0; ct < 4; ++ct)
#pragma unroll
                for (int rr = 0; rr < 4; ++rr) o_red[(ct * 16 + q * 4 + rr) * 68 + nl] = accO[ct][rr];
        }
        __syncthreads();
        if (ph == 0) {
#pragma unroll
            for (int ct = 0; ct < 4; ++ct) {
                us4 ov;
                ov.x = f2bf(accO[ct][0] + o_red[(ct * 16 + q * 4 + 0) * 68 + nl]);
                ov.y = f2bf(accO[ct][1] + o_red[(ct * 16 + q * 4 + 1) * 68 + nl]);
                ov.z = f2bf(accO[ct][2] + o_red[(ct * 16 + q * 4 + 2) * 68 + nl]);
                ov.w = f2bf(accO[ct][3] + o_red[(ct * 16 + q * 4 + 3) * 68 + nl]);
                *(us4*)&o_lds[nl * 72 + ct * 16 + q * 4] = ov;
            }
        }
        __syncthreads();
        // epilogue: finalT[o][n] = wmask @ outT + x ; o-rows split across ph
        bf8 oB0 = *(const bf8*)&o_lds[nl * 72 + q * 8];
        bf8 oB1 = *(const bf8*)&o_lds[nl * 72 + 32 + q * 8];
#pragma unroll
        for (int t2 = 0; t2 < 2; ++t2) {
            int tr = ph * 2 + t2;
            const unsigned short* wa = wmask_bf + (tr * 16 + l16) * 64 + q * 8;
            bf8 w0 = *(const bf8*)wa;
            bf8 w1 = *(const bf8*)(wa + 32);
            f4 accF = {0.f, 0.f, 0.f, 0.f};
            accF = MFMA(w0, oB0, accF);
            accF = MFMA(w1, oB1, accF);
#pragma unroll
            for (int rr = 0; rr < 4; ++rr) {
                size_t ix = bo + (size_t)(tr * 16 + q * 4 + rr) * NN + n0 + nl;
                out[ix] = accF[rr] + x[ix];
            }
        }
    }
}

// ---------------------------------------------------------------------------
extern "C" void kernel_launch(void* const* d_in, const int* in_sizes, int n_in,
                              void* d_out, int out_size, void* d_ws, size_t ws_size,
                              hipStream_t stream) {
    const float* x       = (const float*)d_in[0];
    const float* w_phi   = (const float*)d_in[1];
    const float* w_theta = (const float*)d_in[2];
    const float* w_g     = (const float*)d_in[3];
    const float* w_mask  = (const float*)d_in[4];
    const float* w_mv    = (const float*)d_in[5];
    const float* w_mk    = (const float*)d_in[6];
    float* out = (float*)d_out;

    const size_t CN = (size_t)BB * CC * NN;  // 2,097,152 elements
    char* p = (char*)d_ws;
    unsigned short* theta_nc = (unsigned short*)p; p += CN * 2;
    unsigned short* phi_cm = (unsigned short*)p;   p += CN * 2;
    unsigned short* g2_cm = (unsigned short*)p;    p += CN * 2;
    float* sinv = (float*)p;                       p += CN * 2;  // uses 128 KB of slot
    unsigned short* phi2t = (unsigned short*)p;    p += CN * 2;
    unsigned short* wmk_bf = (unsigned short*)p;   p += (size_t)NN * NN * 2;
    unsigned short* wmask_bf = (unsigned short*)p; p += 4096 * 2;
    unsigned* bar = (unsigned*)p;                  p += 256;  // grid-barrier ticket

    hipMemsetAsync((void*)bar, 0, 256, stream);  // captured into graph, per-iter
    k_all<<<512, 512, 0, stream>>>(x, w_phi, w_theta, w_g, w_mask, w_mv, w_mk,
                                   theta_nc, phi_cm, g2_cm, sinv, phi2t,
                                   wmk_bf, wmask_bf, bar, out);
}

// Round 8
// 132.548 us; speedup vs baseline: 2.3182x; 2.1688x over previous
//
#include <hip/hip_runtime.h>

#define BB 32
#define CC 64
#define NN 1024

typedef __attribute__((ext_vector_type(8))) short bf8;            // 8 bf16 = 4 VGPR (MFMA A/B frag)
typedef __attribute__((ext_vector_type(4))) float f4;             // MFMA C/D frag
typedef __attribute__((ext_vector_type(4))) unsigned short us4;   // 8B packed bf16 store

__device__ __forceinline__ unsigned short f2bf(float f) {
    unsigned u = __float_as_uint(f);
    return (unsigned short)((u + 0x7fffu + ((u >> 16) & 1u)) >> 16);
}
__device__ __forceinline__ float bf2f(unsigned short u) {
    return __uint_as_float(((unsigned)u) << 16);
}

#define MFMA(a, b, c) __builtin_amdgcn_mfma_f32_16x16x32_bf16(a, b, c, 0, 0, 0)

// Async global->LDS DMA, 16 B per lane: LDS dst = wave-uniform base + lane*16.
#define GLDS(g, l)                                                              \
    __builtin_amdgcn_global_load_lds(                                           \
        (const __attribute__((address_space(1))) void*)(g),                     \
        (__attribute__((address_space(3))) void*)(l), 16, 0, 0)

// XCD-aware swizzle for 512-block grids (8 XCDs, round-robin dispatch):
// each XCD owns 4 contiguous batches (64 blocks). 512 % 8 == 0 -> bijective.
__device__ __forceinline__ void swz512(int i, int& b, int& t0) {
    int gid = (i & 7) * 64 + (i >> 3);
    b = gid >> 4;
    t0 = (gid & 15) * 64;
}

// ---------------------------------------------------------------------------
// k0: small prep only (16 blocks x 256): wcat_bf[192][64] = stacked bf16
// weights (rows 0-63 w_theta, 64-127 w_phi, 128-191 w_mv@w_g); wmask -> bf16.
// (wmk fp32->bf16 moved into k1 — distributed over its 1024 blocks.)
// ---------------------------------------------------------------------------
__global__ void k0_prep(const float* __restrict__ w_mv, const float* __restrict__ w_g,
                        const float* __restrict__ w_theta, const float* __restrict__ w_phi,
                        const float* __restrict__ w_mask,
                        unsigned short* __restrict__ wcat_bf,
                        unsigned short* __restrict__ wmask_bf) {
    int idx = blockIdx.x * 256 + threadIdx.x;  // 0..4095
    int d = idx >> 6, e = idx & 63;
    float acc = 0.f;
    for (int c = 0; c < 64; ++c) acc += w_mv[d * 64 + c] * w_g[c * 64 + e];
    wcat_bf[idx] = f2bf(w_theta[idx]);
    wcat_bf[4096 + idx] = f2bf(w_phi[idx]);
    wcat_bf[8192 + idx] = f2bf(acc);
    wmask_bf[idx] = f2bf(w_mask[idx]);
}

// ---------------------------------------------------------------------------
// k1: channel GEMMs via MFMA: out[192][32-tile] = wcat @ x_tile (K=c=64).
// 32-n tiles -> grid (32,B) = 1024 blocks (4 blk/CU, 16 waves/CU).
// Also carries the wmk fp32->bf16 conversion (4 float4/thread, distributed
// over the 1024 blocks; overlaps the x staging latency; consumed by k23
// which launches after k1 completes). x staged via float4 + f2bf ->
// xT[n][c] (pad 72). theta stores [n][c] us4; phi/g2 store [c][n].
// 256 thr / 4 waves; wave w -> wcat rows [48w,48w+48).
// ---------------------------------------------------------------------------
__global__ __launch_bounds__(256, 4) void k1_channel(const float* __restrict__ x,
                                                     const float* __restrict__ w_mk,
                                                     const unsigned short* __restrict__ wcat,
                                                     unsigned short* __restrict__ theta_nc,
                                                     unsigned short* __restrict__ phi_cm,
                                                     unsigned short* __restrict__ g2_cm,
                                                     unsigned short* __restrict__ wmk_bf) {
    __shared__ __align__(16) unsigned short xT[32][72];
    int b = blockIdx.y;
    int n0 = blockIdx.x * 32;
    int tid = threadIdx.x;
    int w = tid >> 6, lane = tid & 63, l16 = lane & 15, q = lane >> 4;
    size_t bo = (size_t)b * CC * NN;
    // wmk slice: block-flat id * 1024 + tid*4 covers NN*NN = 1M elements
    {
        int wi = (b * 32 + blockIdx.x) * 1024 + tid * 4;
        float4 wv = *(const float4*)(w_mk + wi);
        us4 wr;
        wr.x = f2bf(wv.x); wr.y = f2bf(wv.y); wr.z = f2bf(wv.z); wr.w = f2bf(wv.w);
        *(us4*)(wmk_bf + wi) = wr;
    }
#pragma unroll
    for (int i = 0; i < 2; ++i) {
        int f = i * 1024 + tid * 4;
        int c = f >> 5, n = f & 31;
        float4 v = *(const float4*)(x + bo + (size_t)c * NN + n0 + n);
        xT[n + 0][c] = f2bf(v.x);
        xT[n + 1][c] = f2bf(v.y);
        xT[n + 2][c] = f2bf(v.z);
        xT[n + 3][c] = f2bf(v.w);
    }
    __syncthreads();
    bf8 bF[2][2];
#pragma unroll
    for (int ct = 0; ct < 2; ++ct) {
        bF[ct][0] = *(const bf8*)&xT[ct * 16 + l16][q * 8];
        bF[ct][1] = *(const bf8*)&xT[ct * 16 + l16][32 + q * 8];
    }
#pragma unroll
    for (int rt = 0; rt < 3; ++rt) {
        int R = w * 48 + rt * 16;  // wcat row-tile base (16-aligned, within one output)
        const unsigned short* wa = wcat + (R + l16) * 64 + q * 8;
        bf8 a0 = *(const bf8*)wa;
        bf8 a1 = *(const bf8*)(wa + 32);
        int which = R >> 6, rb = R & 63;  // wave-uniform
#pragma unroll
        for (int ct = 0; ct < 2; ++ct) {
            f4 acc = {0.f, 0.f, 0.f, 0.f};
            acc = MFMA(a0, bF[ct][0], acc);
            acc = MFMA(a1, bF[ct][1], acc);
            int n = n0 + ct * 16 + l16;
            if (which == 0) {  // theta: [n][c] layout, rows o contiguous per lane
                us4 t;
                t.x = f2bf(acc[0]); t.y = f2bf(acc[1]);
                t.z = f2bf(acc[2]); t.w = f2bf(acc[3]);
                *(us4*)&theta_nc[bo + (size_t)n * 64 + rb + q * 4] = t;
            } else {
                unsigned short* dst = (which == 1 ? phi_cm : g2_cm) + bo;
#pragma unroll
                for (int r = 0; r < 4; ++r)
                    dst[(size_t)(rb + q * 4 + r) * NN + n] = f2bf(acc[r]);
            }
        }
    }
}

// ---------------------------------------------------------------------------
// k23: fused k2+k3. Phase A (= old k2): phi2t tile [64k][64c] = wmk @ phi^T
// via double-buffered GLDS pipeline (counted vmcnt(3), XOR-swizzled tiles);
// result written to global phi2t AND kept in LDS pT. Phase B (= old k3):
// S[k] = sum_n exp(theta[n] . phi2t[k]); theta rows (128B contiguous) staged
// in 64-row chunks via ONE coalesced GLDS per wave per chunk, double-buffered
// with counted vmcnt(1). phi2t B-frags read from pT (LDS, zero global
// re-read). Writes sinv = 1/S. 512 thr / 8 waves. LDS ~26 KB.
// ---------------------------------------------------------------------------
__global__ __launch_bounds__(512, 4) void k23_phi2_stats(
    const unsigned short* __restrict__ phi_cm,
    const unsigned short* __restrict__ wmk_bf,
    const unsigned short* __restrict__ theta_nc,
    unsigned short* __restrict__ phi2t,
    float* __restrict__ sinv) {
    __shared__ __align__(16) unsigned short bT[2][4096];  // phase A: phi tiles / phase B: theta chunks
    __shared__ __align__(16) unsigned short pT[64][72];   // phi2t tile [k][c], pad 72
    __shared__ float sred[8][32];
    int b, k0;
    swz512(blockIdx.x, b, k0);
    int tid = threadIdx.x;
    int w = tid >> 6, lane = tid & 63, l16 = lane & 15, q = lane >> 4;
    size_t bo = (size_t)b * CC * NN;
    int srow = w * 8 + (lane >> 3);                 // staged row (linear LDS dest)
    int scol = ((lane & 7) ^ (lane >> 3)) * 8;      // pre-swizzled source col (shorts)

    // ================= phase A: phi2t tile =================
    int ks = w & 3, ch = w >> 2;
    const unsigned short* gsrc = phi_cm + bo + (size_t)srow * NN + scol;
    const unsigned short* arow = wmk_bf + (size_t)(k0 + ks * 16 + l16) * NN + q * 8;
    f4 acc[2];
    acc[0] = (f4){0.f, 0.f, 0.f, 0.f};
    acc[1] = (f4){0.f, 0.f, 0.f, 0.f};
    bf8 aC0 = *(const bf8*)(arow);
    bf8 aC1 = *(const bf8*)(arow + 32);
    GLDS(gsrc, &bT[0][w * 512]);
    __syncthreads();  // prologue: tile 0 + A rows 0 ready
#pragma unroll 2
    for (int mc = 0; mc < 16; ++mc) {
        const unsigned short* bTc = bT[mc & 1];
        bf8 aN0 = aC0, aN1 = aC1;
        if (mc < 15) {
            int mn = (mc + 1) * 64;
            aN0 = *(const bf8*)(arow + mn);
            aN1 = *(const bf8*)(arow + mn + 32);
            GLDS(gsrc + mn, &bT[(mc + 1) & 1][w * 512]);
            asm volatile("s_waitcnt vmcnt(3)" ::: "memory");  // cur tile + cur A done
        } else {
            asm volatile("s_waitcnt vmcnt(0)" ::: "memory");
        }
        __builtin_amdgcn_s_barrier();
        __builtin_amdgcn_sched_barrier(0);
#pragma unroll
        for (int t = 0; t < 2; ++t) {
            int row = (ch * 2 + t) * 16 + l16;
            int sw = (row & 7) * 8;
            bf8 b0 = *(const bf8*)&bTc[row * 64 + ((q * 8) ^ sw)];
            bf8 b1 = *(const bf8*)&bTc[row * 64 + ((32 + q * 8) ^ sw)];
            acc[t] = MFMA(aC0, b0, acc[t]);
            acc[t] = MFMA(aC1, b1, acc[t]);
        }
        __builtin_amdgcn_s_barrier();  // all readers done -> next overwrite safe
        __builtin_amdgcn_sched_barrier(0);
        aC0 = aN0;
        aC1 = aN1;
    }
    // epilogue A: tile -> pT (LDS) + phi2t (global, needed by k4)
    unsigned short* prow = phi2t + bo;
#pragma unroll
    for (int t = 0; t < 2; ++t) {
        int ccol = (ch * 2 + t) * 16 + l16;
#pragma unroll
        for (int r = 0; r < 4; ++r) {
            int krow = ks * 16 + q * 4 + r;
            unsigned short v = f2bf(acc[t][r]);
            pT[krow][ccol] = v;
            prow[(size_t)(k0 + krow) * 64 + ccol] = v;
        }
    }

    // ================= phase B: S[k] over all n =================
    int rg = w & 3, th = w >> 2;
    const unsigned short* thsrc = theta_nc + bo + (size_t)srow * 64 + scol;
    GLDS(thsrc, &bT[0][w * 512]);  // theta chunk 0 (overlaps pT write drain)
    __syncthreads();               // drains pT ds_writes + chunk-0 DMA
    bf8 pF[2][2];
#pragma unroll
    for (int t = 0; t < 2; ++t)
#pragma unroll
        for (int kc = 0; kc < 2; ++kc)
            pF[t][kc] = *(const bf8*)&pT[(th * 2 + t) * 16 + l16][kc * 32 + q * 8];
    float s[2] = {0.f, 0.f};
#pragma unroll 2
    for (int nc = 0; nc < 16; ++nc) {
        const unsigned short* tTc = bT[nc & 1];
        if (nc < 15) {
            GLDS(thsrc + (nc + 1) * 4096, &bT[(nc + 1) & 1][w * 512]);
            asm volatile("s_waitcnt vmcnt(1)" ::: "memory");  // cur chunk staged
        } else {
            asm volatile("s_waitcnt vmcnt(0)" ::: "memory");
        }
        __builtin_amdgcn_s_barrier();
        __builtin_amdgcn_sched_barrier(0);
        int r = rg * 16 + l16;
        int sw = (r & 7);
        bf8 a0 = *(const bf8*)&tTc[r * 64 + ((q ^ sw) * 8)];
        bf8 a1 = *(const bf8*)&tTc[r * 64 + (((4 + q) ^ sw) * 8)];
#pragma unroll
        for (int t = 0; t < 2; ++t) {
            f4 at = {0.f, 0.f, 0.f, 0.f};
            at = MFMA(a0, pF[t][0], at);
            at = MFMA(a1, pF[t][1], at);
            s[t] += __expf(at[0]) + __expf(at[1]) + __expf(at[2]) + __expf(at[3]);
        }
        __builtin_amdgcn_s_barrier();  // readers done -> next overwrite safe
        __builtin_amdgcn_sched_barrier(0);
    }
#pragma unroll
    for (int t = 0; t < 2; ++t) {
        s[t] += __shfl_xor(s[t], 16, 64);
        s[t] += __shfl_xor(s[t], 32, 64);
    }
    if (q == 0) {
        sred[w][l16] = s[0];
        sred[w][16 + l16] = s[1];
    }
    __syncthreads();
    if (tid < 64) {
        int th2 = tid >> 5, rem = tid & 31;
        float S = sred[th2 * 4 + 0][rem] + sred[th2 * 4 + 1][rem] +
                  sred[th2 * 4 + 2][rem] + sred[th2 * 4 + 3][rem];
        sinv[(size_t)b * NN + k0 + tid] = 1.f / S;
    }
}

// ---------------------------------------------------------------------------
// k4: per (b, n-tile 64): attT[m][n] = phi2t @ theta^T, P' = exp(attT)*Sinv[m]
// (softmax folded here), outT[c][n] += g2 @ P'^T over 16 m-chunks; epilogue
// finalT = wmask @ outT + x. ONE shared (aT,gT) 64x64 pair per chunk,
// double-buffered, source-swizzled global_load_lds + counted vmcnt(2) across
// raw barriers (T3+T4). Waves: (ws = w&3 -> 16 n's, ph = w>>2 -> m/k-half of
// each chunk); P rows wave-private per (ws,ph); ph-partials reduced at end.
// LDS 45 KB: buf0 aT/gT | buf1 aT/gT | P[64][72] | svs[1024]f32.
// ---------------------------------------------------------------------------
__global__ __launch_bounds__(512, 4) void k4_out(const unsigned short* __restrict__ theta_nc,
                                                 const unsigned short* __restrict__ phi2t,
                                                 const unsigned short* __restrict__ g2_cm,
                                                 const float* __restrict__ sinv,
                                                 const unsigned short* __restrict__ wmask_bf,
                                                 const float* __restrict__ x,
                                                 float* __restrict__ out) {
    __shared__ __align__(16) unsigned short smem[23040];  // 46080 B
    float* svs_l = (float*)(smem + 20992);                // 1024 f32
    int b, n0;
    swz512(blockIdx.x, b, n0);
    int tid = threadIdx.x;
    int w = tid >> 6, lane = tid & 63, l16 = lane & 15, q = lane >> 4;
    int ws = w & 3, ph = w >> 2;
    int nl = ws * 16 + l16;  // lane's n (frag col); P rows wave-private
    size_t bo = (size_t)b * CC * NN;
    int srow = w * 8 + (lane >> 3);             // staged row (m for aT, c for gT)
    int scol = ((lane & 7) ^ (lane >> 3)) * 8;  // pre-swizzled col (shorts)
    const unsigned short* p2b = phi2t + bo;
    const unsigned short* g2b = g2_cm + bo;
    if (tid < 256) *(f4*)&svs_l[tid * 4] = *(const f4*)(sinv + (size_t)b * NN + tid * 4);
    bf8 thB[2];
#pragma unroll
    for (int kc = 0; kc < 2; ++kc)
        thB[kc] = *(const bf8*)(theta_nc + bo + (size_t)(n0 + nl) * 64 + kc * 32 + q * 8);
    f4 accO[4];
#pragma unroll
    for (int ct = 0; ct < 4; ++ct) accO[ct] = (f4){0.f, 0.f, 0.f, 0.f};
    // prologue: stage chunk 0 into buf 0
    GLDS(p2b + (size_t)srow * 64 + scol, smem + w * 512);
    GLDS(g2b + (size_t)srow * NN + scol, smem + 4096 + w * 512);
    __syncthreads();  // drains prologue DMA + svs/thB loads
#pragma unroll 2
    for (int mc = 0; mc < 16; ++mc) {
        unsigned short* aT = smem + (mc & 1) * 8192;  // phi2t chunk [m64][c64]
        unsigned short* gT = aT + 4096;               // g2 chunk [c64][m64]
        if (mc < 15) {
            int mn = (mc + 1) * 64;
            unsigned short* aN = smem + ((mc + 1) & 1) * 8192;
            GLDS(p2b + (size_t)(mn + srow) * 64 + scol, aN + w * 512);
            GLDS(g2b + (size_t)srow * NN + mn + scol, aN + 4096 + w * 512);
            asm volatile("s_waitcnt vmcnt(2)" ::: "memory");  // cur chunk staged
        } else {
            asm volatile("s_waitcnt vmcnt(0)" ::: "memory");
        }
        __builtin_amdgcn_s_barrier();
        __builtin_amdgcn_sched_barrier(0);
        int m0 = mc * 64;
        unsigned short* Pr = smem + 16384 + nl * 72 + ph * 32;
        int swz = (l16 & 7) * 8;
        // GEMM1: att rows (ph-half of chunk) x 16 n-cols; P' = exp * Sinv
#pragma unroll
        for (int mrr = 0; mrr < 2; ++mrr) {
            int rowA = ph * 32 + mrr * 16 + l16;
            bf8 a0 = *(const bf8*)&aT[rowA * 64 + ((q * 8) ^ swz)];
            bf8 a1 = *(const bf8*)&aT[rowA * 64 + ((32 + q * 8) ^ swz)];
            f4 at = {0.f, 0.f, 0.f, 0.f};
            at = MFMA(a0, thB[0], at);
            at = MFMA(a1, thB[1], at);
            f4 sv = *(const f4*)&svs_l[m0 + ph * 32 + mrr * 16 + q * 4];
            us4 pk;
            pk.x = f2bf(__expf(at[0]) * sv[0]);
            pk.y = f2bf(__expf(at[1]) * sv[1]);
            pk.z = f2bf(__expf(at[2]) * sv[2]);
            pk.w = f2bf(__expf(at[3]) * sv[3]);
            *(us4*)&Pr[mrr * 16 + q * 4] = pk;
        }
        // GEMM2: outT[c][n] += g2[c][k in ph-half] * P'[n][k]  (K=32, 1 MFMA/ct)
        bf8 pF = *(const bf8*)&Pr[q * 8];
#pragma unroll
        for (int ct = 0; ct < 4; ++ct) {
            int rowG = ct * 16 + l16;
            bf8 g0 = *(const bf8*)&gT[rowG * 64 + (((ph * 32) + q * 8) ^ swz)];
            accO[ct] = MFMA(g0, pF, accO[ct]);
        }
        __builtin_amdgcn_s_barrier();  // readers done -> next overwrite safe
        __builtin_amdgcn_sched_barrier(0);
    }
    // ph-pair reduction (o_red aliases buf region; o_lds after it)
    float* o_red = (float*)smem;                 // [64][68] f32 = 17408 B
    unsigned short* o_lds = smem + 8704;         // [64][72] bf16
    if (ph == 1) {
#pragma unroll
        for (int ct = 0; ct < 4; ++ct)
#pragma unroll
            for (int r = 0; r < 4; ++r) o_red[(ct * 16 + q * 4 + r) * 68 + nl] = accO[ct][r];
    }
    __syncthreads();
    if (ph == 0) {
#pragma unroll
        for (int ct = 0; ct < 4; ++ct) {
            us4 ov;
            ov.x = f2bf(accO[ct][0] + o_red[(ct * 16 + q * 4 + 0) * 68 + nl]);
            ov.y = f2bf(accO[ct][1] + o_red[(ct * 16 + q * 4 + 1) * 68 + nl]);
            ov.z = f2bf(accO[ct][2] + o_red[(ct * 16 + q * 4 + 2) * 68 + nl]);
            ov.w = f2bf(accO[ct][3] + o_red[(ct * 16 + q * 4 + 3) * 68 + nl]);
            *(us4*)&o_lds[nl * 72 + ct * 16 + q * 4] = ov;
        }
    }
    __syncthreads();
    // epilogue: finalT[o][n] = wmask @ outT + x ; o-rows split across ph
    bf8 oB0 = *(const bf8*)&o_lds[nl * 72 + q * 8];
    bf8 oB1 = *(const bf8*)&o_lds[nl * 72 + 32 + q * 8];
#pragma unroll
    for (int t2 = 0; t2 < 2; ++t2) {
        int tr = ph * 2 + t2;
        const unsigned short* wa = wmask_bf + (tr * 16 + l16) * 64 + q * 8;
        bf8 w0 = *(const bf8*)wa;
        bf8 w1 = *(const bf8*)(wa + 32);
        f4 accF = {0.f, 0.f, 0.f, 0.f};
        accF = MFMA(w0, oB0, accF);
        accF = MFMA(w1, oB1, accF);
#pragma unroll
        for (int r = 0; r < 4; ++r) {
            size_t ix = bo + (size_t)(tr * 16 + q * 4 + r) * NN + n0 + nl;
            out[ix] = accF[r] + x[ix];
        }
    }
}

// ---------------------------------------------------------------------------
extern "C" void kernel_launch(void* const* d_in, const int* in_sizes, int n_in,
                              void* d_out, int out_size, void* d_ws, size_t ws_size,
                              hipStream_t stream) {
    const float* x       = (const float*)d_in[0];
    const float* w_phi   = (const float*)d_in[1];
    const float* w_theta = (const float*)d_in[2];
    const float* w_g     = (const float*)d_in[3];
    const float* w_mask  = (const float*)d_in[4];
    const float* w_mv    = (const float*)d_in[5];
    const float* w_mk    = (const float*)d_in[6];
    float* out = (float*)d_out;

    const size_t CN = (size_t)BB * CC * NN;  // 2,097,152 elements
    char* p = (char*)d_ws;
    unsigned short* theta_nc = (unsigned short*)p; p += CN * 2;
    unsigned short* phi_cm = (unsigned short*)p;   p += CN * 2;
    unsigned short* g2_cm = (unsigned short*)p;    p += CN * 2;
    float* sinv = (float*)p;                       p += CN * 2;  // uses 128 KB of slot
    unsigned short* phi2t = (unsigned short*)p;    p += CN * 2;
    unsigned short* wmk_bf = (unsigned short*)p;   p += (size_t)NN * NN * 2;
    unsigned short* wcat_bf = (unsigned short*)p;  p += 192 * 64 * 2;
    unsigned short* wmask_bf = (unsigned short*)p; p += 4096 * 2;

    k0_prep<<<16, 256, 0, stream>>>(w_mv, w_g, w_theta, w_phi, w_mask,
                                    wcat_bf, wmask_bf);
    k1_channel<<<dim3(32, BB), 256, 0, stream>>>(x, w_mk, wcat_bf, theta_nc,
                                                 phi_cm, g2_cm, wmk_bf);
    k23_phi2_stats<<<512, 512, 0, stream>>>(phi_cm, wmk_bf, theta_nc, phi2t, sinv);
    k4_out<<<512, 512, 0, stream>>>(theta_nc, phi2t, g2_cm, sinv, wmask_bf, x, out);
}

// Round 9
// 131.421 us; speedup vs baseline: 2.3380x; 1.0086x over previous
//
#include <hip/hip_runtime.h>

#define BB 32
#define CC 64
#define NN 1024

typedef __attribute__((ext_vector_type(8))) short bf8;            // 8 bf16 = 4 VGPR (MFMA A/B frag)
typedef __attribute__((ext_vector_type(4))) float f4;             // MFMA C/D frag
typedef __attribute__((ext_vector_type(4))) unsigned short us4;   // 8B packed bf16 store

__device__ __forceinline__ unsigned short f2bf(float f) {
    unsigned u = __float_as_uint(f);
    return (unsigned short)((u + 0x7fffu + ((u >> 16) & 1u)) >> 16);
}
__device__ __forceinline__ float bf2f(unsigned short u) {
    return __uint_as_float(((unsigned)u) << 16);
}

#define MFMA(a, b, c) __builtin_amdgcn_mfma_f32_16x16x32_bf16(a, b, c, 0, 0, 0)

// Async global->LDS DMA, 16 B per lane: LDS dst = wave-uniform base + lane*16.
#define GLDS(g, l)                                                              \
    __builtin_amdgcn_global_load_lds(                                           \
        (const __attribute__((address_space(1))) void*)(g),                     \
        (__attribute__((address_space(3))) void*)(l), 16, 0, 0)

// XCD-aware swizzle for 512-block grids (8 XCDs, round-robin dispatch):
// each XCD owns 4 contiguous batches (64 blocks). 512 % 8 == 0 -> bijective.
__device__ __forceinline__ void swz512(int i, int& b, int& t0) {
    int gid = (i & 7) * 64 + (i >> 3);
    b = gid >> 4;
    t0 = (gid & 15) * 64;
}

// ---------------------------------------------------------------------------
// k0: small prep only (16 blocks x 256): wcat_bf[192][64] = stacked bf16
// weights (rows 0-63 w_theta, 64-127 w_phi, 128-191 w_mv@w_g); wmask -> bf16.
// ---------------------------------------------------------------------------
__global__ void k0_prep(const float* __restrict__ w_mv, const float* __restrict__ w_g,
                        const float* __restrict__ w_theta, const float* __restrict__ w_phi,
                        const float* __restrict__ w_mask,
                        unsigned short* __restrict__ wcat_bf,
                        unsigned short* __restrict__ wmask_bf) {
    int idx = blockIdx.x * 256 + threadIdx.x;  // 0..4095
    int d = idx >> 6, e = idx & 63;
    float acc = 0.f;
    for (int c = 0; c < 64; ++c) acc += w_mv[d * 64 + c] * w_g[c * 64 + e];
    wcat_bf[idx] = f2bf(w_theta[idx]);
    wcat_bf[4096 + idx] = f2bf(w_phi[idx]);
    wcat_bf[8192 + idx] = f2bf(acc);
    wmask_bf[idx] = f2bf(w_mask[idx]);
}

// ---------------------------------------------------------------------------
// k1: channel GEMMs via MFMA: out[192][32-tile] = wcat @ x_tile (K=c=64).
// 32-n tiles -> grid (32,B) = 1024 blocks (4 blk/CU, 16 waves/CU).
// Also carries the wmk fp32->bf16 conversion (4 float4/thread, distributed
// over the 1024 blocks; consumed by k23 after k1 completes). x staged via
// float4 + f2bf -> xT[n][c] (pad 72). theta stores [n][c] us4; phi/g2 store
// [c][n]. 256 thr / 4 waves; wave w -> wcat rows [48w,48w+48).
// ---------------------------------------------------------------------------
__global__ __launch_bounds__(256, 4) void k1_channel(const float* __restrict__ x,
                                                     const float* __restrict__ w_mk,
                                                     const unsigned short* __restrict__ wcat,
                                                     unsigned short* __restrict__ theta_nc,
                                                     unsigned short* __restrict__ phi_cm,
                                                     unsigned short* __restrict__ g2_cm,
                                                     unsigned short* __restrict__ wmk_bf) {
    __shared__ __align__(16) unsigned short xT[32][72];
    int b = blockIdx.y;
    int n0 = blockIdx.x * 32;
    int tid = threadIdx.x;
    int w = tid >> 6, lane = tid & 63, l16 = lane & 15, q = lane >> 4;
    size_t bo = (size_t)b * CC * NN;
    // wmk slice: block-flat id * 1024 + tid*4 covers NN*NN = 1M elements
    {
        int wi = (b * 32 + blockIdx.x) * 1024 + tid * 4;
        float4 wv = *(const float4*)(w_mk + wi);
        us4 wr;
        wr.x = f2bf(wv.x); wr.y = f2bf(wv.y); wr.z = f2bf(wv.z); wr.w = f2bf(wv.w);
        *(us4*)(wmk_bf + wi) = wr;
    }
#pragma unroll
    for (int i = 0; i < 2; ++i) {
        int f = i * 1024 + tid * 4;
        int c = f >> 5, n = f & 31;
        float4 v = *(const float4*)(x + bo + (size_t)c * NN + n0 + n);
        xT[n + 0][c] = f2bf(v.x);
        xT[n + 1][c] = f2bf(v.y);
        xT[n + 2][c] = f2bf(v.z);
        xT[n + 3][c] = f2bf(v.w);
    }
    __syncthreads();
    bf8 bF[2][2];
#pragma unroll
    for (int ct = 0; ct < 2; ++ct) {
        bF[ct][0] = *(const bf8*)&xT[ct * 16 + l16][q * 8];
        bF[ct][1] = *(const bf8*)&xT[ct * 16 + l16][32 + q * 8];
    }
#pragma unroll
    for (int rt = 0; rt < 3; ++rt) {
        int R = w * 48 + rt * 16;  // wcat row-tile base (16-aligned, within one output)
        const unsigned short* wa = wcat + (R + l16) * 64 + q * 8;
        bf8 a0 = *(const bf8*)wa;
        bf8 a1 = *(const bf8*)(wa + 32);
        int which = R >> 6, rb = R & 63;  // wave-uniform
#pragma unroll
        for (int ct = 0; ct < 2; ++ct) {
            f4 acc = {0.f, 0.f, 0.f, 0.f};
            acc = MFMA(a0, bF[ct][0], acc);
            acc = MFMA(a1, bF[ct][1], acc);
            int n = n0 + ct * 16 + l16;
            if (which == 0) {  // theta: [n][c] layout, rows o contiguous per lane
                us4 t;
                t.x = f2bf(acc[0]); t.y = f2bf(acc[1]);
                t.z = f2bf(acc[2]); t.w = f2bf(acc[3]);
                *(us4*)&theta_nc[bo + (size_t)n * 64 + rb + q * 4] = t;
            } else {
                unsigned short* dst = (which == 1 ? phi_cm : g2_cm) + bo;
#pragma unroll
                for (int r = 0; r < 4; ++r)
                    dst[(size_t)(rb + q * 4 + r) * NN + n] = f2bf(acc[r]);
            }
        }
    }
}

// ---------------------------------------------------------------------------
// k23: fused k2+k3, BK=128 (barrier pairs halved 16->8 per phase; 2x MFMA
// per sync window; counted vmcnt keeps next chunk's DMA + A-prefetch in
// flight across barriers).
// Phase A: phi2t tile [64k][64c] = wmk @ phi^T. phi chunks [64c][128m]
// (16 groups/row, group ^= row&7 swizzle; source pre-swizzled; 2 GLDS/wave +
// 4 wmk A-frag prefetches per iter; vmcnt(6)). Tile kept in LDS pT + written
// to global. Phase B: S[k] = sum_n exp(theta[n].phi2t[k]); theta chunks of
// 128 rows (2 GLDS/wave, vmcnt(2)); phi2t B-frags from pT. sinv = 1/S.
// MFMA/exp accumulation order identical to BK=64 version -> bit-identical.
// 512 thr / 8 waves. LDS 43 KB.
// ---------------------------------------------------------------------------
__global__ __launch_bounds__(512, 4) void k23_phi2_stats(
    const unsigned short* __restrict__ phi_cm,
    const unsigned short* __restrict__ wmk_bf,
    const unsigned short* __restrict__ theta_nc,
    unsigned short* __restrict__ phi2t,
    float* __restrict__ sinv) {
    __shared__ __align__(16) unsigned short bT[2][8192];  // 128-wide chunks
    __shared__ __align__(16) unsigned short pT[64][72];   // phi2t tile [k][c], pad 72
    __shared__ float sred[8][32];
    int b, k0;
    swz512(blockIdx.x, b, k0);
    int tid = threadIdx.x;
    int w = tid >> 6, lane = tid & 63, l16 = lane & 15, q = lane >> 4;
    size_t bo = (size_t)b * CC * NN;

    // ================= phase A: phi2t tile =================
    int ks = w & 3, ch = w >> 2;
    // staging (rows of 128 shorts = 16 groups of 8; 8 rows/wave via 2 GLDS):
    int arow0 = w * 8 + (lane >> 4);                   // GLDS#0 c-row
    int acol0 = ((lane & 15) ^ (arow0 & 7)) * 8;       // pre-swizzled m-group
    int arow1 = arow0 + 4;                             // GLDS#1 c-row
    int acol1 = ((lane & 15) ^ (arow1 & 7)) * 8;
    const unsigned short* ga0 = phi_cm + bo + (size_t)arow0 * NN + acol0;
    const unsigned short* ga1 = phi_cm + bo + (size_t)arow1 * NN + acol1;
    const unsigned short* krow = wmk_bf + (size_t)(k0 + ks * 16 + l16) * NN + q * 8;
    f4 acc[2];
    acc[0] = (f4){0.f, 0.f, 0.f, 0.f};
    acc[1] = (f4){0.f, 0.f, 0.f, 0.f};
    bf8 aC[4], aN[4];
#pragma unroll
    for (int kk = 0; kk < 4; ++kk) aC[kk] = *(const bf8*)(krow + kk * 32);
    GLDS(ga0, &bT[0][(w * 8) * 128]);
    GLDS(ga1, &bT[0][(w * 8 + 4) * 128]);
    __syncthreads();  // prologue: chunk 0 + A frags 0 ready
#pragma unroll 2
    for (int mc = 0; mc < 8; ++mc) {
        const unsigned short* buf = bT[mc & 1];
        if (mc < 7) {
            int mn = (mc + 1) * 128;
#pragma unroll
            for (int kk = 0; kk < 4; ++kk) aN[kk] = *(const bf8*)(krow + mn + kk * 32);
            GLDS(ga0 + mn, &bT[(mc + 1) & 1][(w * 8) * 128]);
            GLDS(ga1 + mn, &bT[(mc + 1) & 1][(w * 8 + 4) * 128]);
            asm volatile("s_waitcnt vmcnt(6)" ::: "memory");  // prev chunk + prev A done
        } else {
            asm volatile("s_waitcnt vmcnt(0)" ::: "memory");
        }
        __builtin_amdgcn_s_barrier();
        __builtin_amdgcn_sched_barrier(0);
#pragma unroll
        for (int t = 0; t < 2; ++t) {
            int row = (ch * 2 + t) * 16 + l16;
            int r7 = row & 7;
#pragma unroll
            for (int kk = 0; kk < 4; ++kk) {
                bf8 bb = *(const bf8*)&buf[row * 128 + (((kk * 4 + q) ^ r7) * 8)];
                acc[t] = MFMA(aC[kk], bb, acc[t]);
            }
        }
        __builtin_amdgcn_s_barrier();  // all readers done -> next overwrite safe
        __builtin_amdgcn_sched_barrier(0);
#pragma unroll
        for (int kk = 0; kk < 4; ++kk) aC[kk] = aN[kk];
    }
    // epilogue A: tile -> pT (LDS) + phi2t (global, needed by k4)
    unsigned short* prow = phi2t + bo;
#pragma unroll
    for (int t = 0; t < 2; ++t) {
        int ccol = (ch * 2 + t) * 16 + l16;
#pragma unroll
        for (int r = 0; r < 4; ++r) {
            int krow2 = ks * 16 + q * 4 + r;
            unsigned short v = f2bf(acc[t][r]);
            pT[krow2][ccol] = v;
            prow[(size_t)(k0 + krow2) * 64 + ccol] = v;
        }
    }

    // ================= phase B: S[k] over all n =================
    int rg = w & 3, th = w >> 2;
    // staging (rows of 64 shorts = 8 groups; 16 rows/wave via 2 GLDS):
    int trow0 = w * 16 + (lane >> 3);                  // GLDS#0 n-row
    int tcol0 = ((lane & 7) ^ (trow0 & 7)) * 8;        // pre-swizzled c-group
    const unsigned short* gt0 = theta_nc + bo + (size_t)trow0 * 64 + tcol0;
    const unsigned short* gt1 = gt0 + 8 * 64;          // rows +8: same (row&7) -> same col
    GLDS(gt0, &bT[0][(w * 16) * 64]);
    GLDS(gt1, &bT[0][(w * 16 + 8) * 64]);
    __syncthreads();  // drains pT ds_writes + chunk-0 DMA
    bf8 pF[2][2];
#pragma unroll
    for (int t = 0; t < 2; ++t)
#pragma unroll
        for (int kc = 0; kc < 2; ++kc)
            pF[t][kc] = *(const bf8*)&pT[(th * 2 + t) * 16 + l16][kc * 32 + q * 8];
    float s[2] = {0.f, 0.f};
#pragma unroll 2
    for (int nc = 0; nc < 8; ++nc) {
        const unsigned short* buf = bT[nc & 1];
        if (nc < 7) {
            GLDS(gt0 + (nc + 1) * 8192, &bT[(nc + 1) & 1][(w * 16) * 64]);
            GLDS(gt1 + (nc + 1) * 8192, &bT[(nc + 1) & 1][(w * 16 + 8) * 64]);
            asm volatile("s_waitcnt vmcnt(2)" ::: "memory");  // prev chunk done
        } else {
            asm volatile("s_waitcnt vmcnt(0)" ::: "memory");
        }
        __builtin_amdgcn_s_barrier();
        __builtin_amdgcn_sched_barrier(0);
#pragma unroll
        for (int half = 0; half < 2; ++half) {
            int r = half * 64 + rg * 16 + l16;
            int r7 = r & 7;
            bf8 a0 = *(const bf8*)&buf[r * 64 + ((q ^ r7) * 8)];
            bf8 a1 = *(const bf8*)&buf[r * 64 + (((4 + q) ^ r7) * 8)];
#pragma unroll
            for (int t = 0; t < 2; ++t) {
                f4 at = {0.f, 0.f, 0.f, 0.f};
                at = MFMA(a0, pF[t][0], at);
                at = MFMA(a1, pF[t][1], at);
                s[t] += __expf(at[0]) + __expf(at[1]) + __expf(at[2]) + __expf(at[3]);
            }
        }
        __builtin_amdgcn_s_barrier();  // readers done -> next overwrite safe
        __builtin_amdgcn_sched_barrier(0);
    }
#pragma unroll
    for (int t = 0; t < 2; ++t) {
        s[t] += __shfl_xor(s[t], 16, 64);
        s[t] += __shfl_xor(s[t], 32, 64);
    }
    if (q == 0) {
        sred[w][l16] = s[0];
        sred[w][16 + l16] = s[1];
    }
    __syncthreads();
    if (tid < 64) {
        int th2 = tid >> 5, rem = tid & 31;
        float S = sred[th2 * 4 + 0][rem] + sred[th2 * 4 + 1][rem] +
                  sred[th2 * 4 + 2][rem] + sred[th2 * 4 + 3][rem];
        sinv[(size_t)b * NN + k0 + tid] = 1.f / S;
    }
}

// ---------------------------------------------------------------------------
// k4: per (b, n-tile 64): attT[m][n] = phi2t @ theta^T, P' = exp(attT)*Sinv[m]
// (softmax folded here), outT[c][n] += g2 @ P'^T over 16 m-chunks; epilogue
// finalT = wmask @ outT + x. ONE shared (aT,gT) 64x64 pair per chunk,
// double-buffered, source-swizzled global_load_lds + counted vmcnt(2) across
// raw barriers (T3+T4). Waves: (ws = w&3 -> 16 n's, ph = w>>2 -> m/k-half of
// each chunk); P rows wave-private per (ws,ph); ph-partials reduced at end.
// LDS 45 KB: buf0 aT/gT | buf1 aT/gT | P[64][72] | svs[1024]f32.
// ---------------------------------------------------------------------------
__global__ __launch_bounds__(512, 4) void k4_out(const unsigned short* __restrict__ theta_nc,
                                                 const unsigned short* __restrict__ phi2t,
                                                 const unsigned short* __restrict__ g2_cm,
                                                 const float* __restrict__ sinv,
                                                 const unsigned short* __restrict__ wmask_bf,
                                                 const float* __restrict__ x,
                                                 float* __restrict__ out) {
    __shared__ __align__(16) unsigned short smem[23040];  // 46080 B
    float* svs_l = (float*)(smem + 20992);                // 1024 f32
    int b, n0;
    swz512(blockIdx.x, b, n0);
    int tid = threadIdx.x;
    int w = tid >> 6, lane = tid & 63, l16 = lane & 15, q = lane >> 4;
    int ws = w & 3, ph = w >> 2;
    int nl = ws * 16 + l16;  // lane's n (frag col); P rows wave-private
    size_t bo = (size_t)b * CC * NN;
    int srow = w * 8 + (lane >> 3);             // staged row (m for aT, c for gT)
    int scol = ((lane & 7) ^ (lane >> 3)) * 8;  // pre-swizzled col (shorts)
    const unsigned short* p2b = phi2t + bo;
    const unsigned short* g2b = g2_cm + bo;
    if (tid < 256) *(f4*)&svs_l[tid * 4] = *(const f4*)(sinv + (size_t)b * NN + tid * 4);
    bf8 thB[2];
#pragma unroll
    for (int kc = 0; kc < 2; ++kc)
        thB[kc] = *(const bf8*)(theta_nc + bo + (size_t)(n0 + nl) * 64 + kc * 32 + q * 8);
    f4 accO[4];
#pragma unroll
    for (int ct = 0; ct < 4; ++ct) accO[ct] = (f4){0.f, 0.f, 0.f, 0.f};
    // prologue: stage chunk 0 into buf 0
    GLDS(p2b + (size_t)srow * 64 + scol, smem + w * 512);
    GLDS(g2b + (size_t)srow * NN + scol, smem + 4096 + w * 512);
    __syncthreads();  // drains prologue DMA + svs/thB loads
#pragma unroll 2
    for (int mc = 0; mc < 16; ++mc) {
        unsigned short* aT = smem + (mc & 1) * 8192;  // phi2t chunk [m64][c64]
        unsigned short* gT = aT + 4096;               // g2 chunk [c64][m64]
        if (mc < 15) {
            int mn = (mc + 1) * 64;
            unsigned short* aN = smem + ((mc + 1) & 1) * 8192;
            GLDS(p2b + (size_t)(mn + srow) * 64 + scol, aN + w * 512);
            GLDS(g2b + (size_t)srow * NN + mn + scol, aN + 4096 + w * 512);
            asm volatile("s_waitcnt vmcnt(2)" ::: "memory");  // cur chunk staged
        } else {
            asm volatile("s_waitcnt vmcnt(0)" ::: "memory");
        }
        __builtin_amdgcn_s_barrier();
        __builtin_amdgcn_sched_barrier(0);
        int m0 = mc * 64;
        unsigned short* Pr = smem + 16384 + nl * 72 + ph * 32;
        int swz = (l16 & 7) * 8;
        // GEMM1: att rows (ph-half of chunk) x 16 n-cols; P' = exp * Sinv
#pragma unroll
        for (int mrr = 0; mrr < 2; ++mrr) {
            int rowA = ph * 32 + mrr * 16 + l16;
            bf8 a0 = *(const bf8*)&aT[rowA * 64 + ((q * 8) ^ swz)];
            bf8 a1 = *(const bf8*)&aT[rowA * 64 + ((32 + q * 8) ^ swz)];
            f4 at = {0.f, 0.f, 0.f, 0.f};
            at = MFMA(a0, thB[0], at);
            at = MFMA(a1, thB[1], at);
            f4 sv = *(const f4*)&svs_l[m0 + ph * 32 + mrr * 16 + q * 4];
            us4 pk;
            pk.x = f2bf(__expf(at[0]) * sv[0]);
            pk.y = f2bf(__expf(at[1]) * sv[1]);
            pk.z = f2bf(__expf(at[2]) * sv[2]);
            pk.w = f2bf(__expf(at[3]) * sv[3]);
            *(us4*)&Pr[mrr * 16 + q * 4] = pk;
        }
        // GEMM2: outT[c][n] += g2[c][k in ph-half] * P'[n][k]  (K=32, 1 MFMA/ct)
        bf8 pF = *(const bf8*)&Pr[q * 8];
#pragma unroll
        for (int ct = 0; ct < 4; ++ct) {
            int rowG = ct * 16 + l16;
            bf8 g0 = *(const bf8*)&gT[rowG * 64 + (((ph * 32) + q * 8) ^ swz)];
            accO[ct] = MFMA(g0, pF, accO[ct]);
        }
        __builtin_amdgcn_s_barrier();  // readers done -> next overwrite safe
        __builtin_amdgcn_sched_barrier(0);
    }
    // ph-pair reduction (o_red aliases buf region; o_lds after it)
    float* o_red = (float*)smem;                 // [64][68] f32 = 17408 B
    unsigned short* o_lds = smem + 8704;         // [64][72] bf16
    if (ph == 1) {
#pragma unroll
        for (int ct = 0; ct < 4; ++ct)
#pragma unroll
            for (int r = 0; r < 4; ++r) o_red[(ct * 16 + q * 4 + r) * 68 + nl] = accO[ct][r];
    }
    __syncthreads();
    if (ph == 0) {
#pragma unroll
        for (int ct = 0; ct < 4; ++ct) {
            us4 ov;
            ov.x = f2bf(accO[ct][0] + o_red[(ct * 16 + q * 4 + 0) * 68 + nl]);
            ov.y = f2bf(accO[ct][1] + o_red[(ct * 16 + q * 4 + 1) * 68 + nl]);
            ov.z = f2bf(accO[ct][2] + o_red[(ct * 16 + q * 4 + 2) * 68 + nl]);
            ov.w = f2bf(accO[ct][3] + o_red[(ct * 16 + q * 4 + 3) * 68 + nl]);
            *(us4*)&o_lds[nl * 72 + ct * 16 + q * 4] = ov;
        }
    }
    __syncthreads();
    // epilogue: finalT[o][n] = wmask @ outT + x ; o-rows split across ph
    bf8 oB0 = *(const bf8*)&o_lds[nl * 72 + q * 8];
    bf8 oB1 = *(const bf8*)&o_lds[nl * 72 + 32 + q * 8];
#pragma unroll
    for (int t2 = 0; t2 < 2; ++t2) {
        int tr = ph * 2 + t2;
        const unsigned short* wa = wmask_bf + (tr * 16 + l16) * 64 + q * 8;
        bf8 w0 = *(const bf8*)wa;
        bf8 w1 = *(const bf8*)(wa + 32);
        f4 accF = {0.f, 0.f, 0.f, 0.f};
        accF = MFMA(w0, oB0, accF);
        accF = MFMA(w1, oB1, accF);
#pragma unroll
        for (int r = 0; r < 4; ++r) {
            size_t ix = bo + (size_t)(tr * 16 + q * 4 + r) * NN + n0 + nl;
            out[ix] = accF[r] + x[ix];
        }
    }
}

// ---------------------------------------------------------------------------
extern "C" void kernel_launch(void* const* d_in, const int* in_sizes, int n_in,
                              void* d_out, int out_size, void* d_ws, size_t ws_size,
                              hipStream_t stream) {
    const float* x       = (const float*)d_in[0];
    const float* w_phi   = (const float*)d_in[1];
    const float* w_theta = (const float*)d_in[2];
    const float* w_g     = (const float*)d_in[3];
    const float* w_mask  = (const float*)d_in[4];
    const float* w_mv    = (const float*)d_in[5];
    const float* w_mk    = (const float*)d_in[6];
    float* out = (float*)d_out;

    const size_t CN = (size_t)BB * CC * NN;  // 2,097,152 elements
    char* p = (char*)d_ws;
    unsigned short* theta_nc = (unsigned short*)p; p += CN * 2;
    unsigned short* phi_cm = (unsigned short*)p;   p += CN * 2;
    unsigned short* g2_cm = (unsigned short*)p;    p += CN * 2;
    float* sinv = (float*)p;                       p += CN * 2;  // uses 128 KB of slot
    unsigned short* phi2t = (unsigned short*)p;    p += CN * 2;
    unsigned short* wmk_bf = (unsigned short*)p;   p += (size_t)NN * NN * 2;
    unsigned short* wcat_bf = (unsigned short*)p;  p += 192 * 64 * 2;
    unsigned short* wmask_bf = (unsigned short*)p; p += 4096 * 2;

    k0_prep<<<16, 256, 0, stream>>>(w_mv, w_g, w_theta, w_phi, w_mask,
                                    wcat_bf, wmask_bf);
    k1_channel<<<dim3(32, BB), 256, 0, stream>>>(x, w_mk, wcat_bf, theta_nc,
                                                 phi_cm, g2_cm, wmk_bf);
    k23_phi2_stats<<<512, 512, 0, stream>>>(phi_cm, wmk_bf, theta_nc, phi2t, sinv);
    k4_out<<<512, 512, 0, stream>>>(theta_nc, phi2t, g2_cm, sinv, wmask_bf, x, out);
}